// Round 5
// baseline (1221.376 us; speedup 1.0000x reference)
//
#include <hip/hip_runtime.h>
#include <hip/hip_bf16.h>
#include <math.h>
#include <cstdint>

static constexpr int NN = 50000;   // nodes
static constexpr int NE = 400000;  // edges
static constexpr int H  = 400;     // hidden dim
static constexpr int NG = 128;     // graphs
static constexpr int NC = 10;      // classes
static constexpr float EPS = 1e-5f;
static constexpr int NB1 = (NN + 255) / 256;   // 196 scan blocks

typedef unsigned short u16;
typedef __attribute__((ext_vector_type(8))) unsigned short u16x8;
typedef __attribute__((ext_vector_type(4))) unsigned short u16x4;
typedef __attribute__((ext_vector_type(8))) short bf16x8;
typedef __attribute__((ext_vector_type(4))) float f32x4;

__device__ __forceinline__ float bf2f(u16 u) {
    return __uint_as_float(((uint32_t)u) << 16);
}
__device__ __forceinline__ u16 f2bf(float f) {
    uint32_t u = __float_as_uint(f);
    return (u16)((u + 0x7FFFu + ((u >> 16) & 1u)) >> 16);
}

// ---------------- CSR build ----------------

__global__ void k_count(const int* __restrict__ dst, int* __restrict__ deg) {
    int e = blockIdx.x * blockDim.x + threadIdx.x;
    if (e < NE) atomicAdd(&deg[dst[e]], 1);
}

__global__ __launch_bounds__(256) void k_scan1(const int* __restrict__ deg,
                                               int* __restrict__ part,
                                               int* __restrict__ btot) {
    __shared__ int sd[256];
    int t = threadIdx.x;
    int i = blockIdx.x * 256 + t;
    int v = (i < NN) ? deg[i] : 0;
    sd[t] = v;
    __syncthreads();
#pragma unroll
    for (int off = 1; off < 256; off <<= 1) {
        int x = (t >= off) ? sd[t - off] : 0;
        __syncthreads();
        sd[t] += x;
        __syncthreads();
    }
    if (i < NN) part[i] = sd[t];
    if (t == 255) btot[blockIdx.x] = sd[255];
}

__global__ __launch_bounds__(256) void k_scan2(int* __restrict__ btot) {
    __shared__ int sd[256];
    int t = threadIdx.x;
    int v = (t < NB1) ? btot[t] : 0;
    sd[t] = v;
    __syncthreads();
#pragma unroll
    for (int off = 1; off < 256; off <<= 1) {
        int x = (t >= off) ? sd[t - off] : 0;
        __syncthreads();
        sd[t] += x;
        __syncthreads();
    }
    if (t < NB1) btot[t] = sd[t];
}

__global__ __launch_bounds__(256) void k_scan3(const int* __restrict__ part,
                                               const int* __restrict__ btot,
                                               const int* __restrict__ deg,
                                               int* __restrict__ rowp,
                                               int* __restrict__ cur) {
    int i = blockIdx.x * 256 + threadIdx.x;
    if (i < NN) {
        int s = part[i] + (blockIdx.x ? btot[blockIdx.x - 1] : 0);
        rowp[i + 1] = s;
        cur[i] = s - deg[i];
    }
    if (i == 0) rowp[0] = 0;
}

__global__ void k_scatter(const int* __restrict__ src, const int* __restrict__ dst,
                          int* __restrict__ cur, int* __restrict__ csrc) {
    int e = blockIdx.x * blockDim.x + threadIdx.x;
    if (e < NE) {
        int d = dst[e];
        int p = atomicAdd(&cur[d], 1);
        csrc[p] = src[e];
    }
}

// ---------------- weights fp32 -> bf16 (all 8*H*H elems in one kernel) ----------------

__global__ void k_cvtw_all(const float* __restrict__ s0, const float* __restrict__ s1,
                           const float* __restrict__ s2, const float* __restrict__ s3,
                           const float* __restrict__ s4, u16* __restrict__ dst) {
    const int Q = H * H / 4;   // 40000 float4 per H*H
    int i = blockIdx.x * blockDim.x + threadIdx.x;   // over 8*Q
    if (i >= 8 * Q) return;
    const float* s;
    int j;
    if (i < Q)            { s = s0; j = i; }
    else if (i < 2 * Q)   { s = s1; j = i - Q; }
    else if (i < 4 * Q)   { s = s2; j = i - 2 * Q; }
    else if (i < 6 * Q)   { s = s3; j = i - 4 * Q; }
    else                  { s = s4; j = i - 6 * Q; }
    float4 v = ((const float4*)s)[j];
    u16x4 o;
    o[0] = f2bf(v.x); o[1] = f2bf(v.y); o[2] = f2bf(v.z); o[3] = f2bf(v.w);
    *(u16x4*)(dst + (size_t)i * 4) = o;
}

// ---------------- aggregation ----------------

__global__ void k_agg0(const float* __restrict__ x, const int* __restrict__ rowp,
                       const int* __restrict__ csrc, float* __restrict__ out) {
    int n = blockIdx.x * blockDim.x + threadIdx.x;
    if (n >= NN) return;
    float4 acc = make_float4(0.f, 0.f, 0.f, 0.f);
    int b = rowp[n], e = rowp[n + 1];
    for (int p = b; p < e; ++p) {
        float4 v = ((const float4*)x)[csrc[p]];
        acc.x += v.x; acc.y += v.y; acc.z += v.z; acc.w += v.w;
    }
    ((float4*)out)[n] = acc;
}

// one wave per node; lanes 0..49 each own 8 contiguous features
__global__ __launch_bounds__(256) void k_aggH(const u16* __restrict__ h,
                                              const int* __restrict__ rowp,
                                              const int* __restrict__ csrc,
                                              u16* __restrict__ out) {
    int n = (blockIdx.x << 2) + (threadIdx.x >> 6);
    if (n >= NN) return;
    int l = threadIdx.x & 63;
    if (l >= 50) return;
    int b = rowp[n], e = rowp[n + 1];
    float acc[8] = {0.f, 0.f, 0.f, 0.f, 0.f, 0.f, 0.f, 0.f};
    for (int p = b; p < e; ++p) {
        const u16* r = h + (long)csrc[p] * H + l * 8;
        u16x8 v = *(const u16x8*)r;
#pragma unroll
        for (int q = 0; q < 8; ++q) acc[q] += bf2f(v[q]);
    }
    u16x8 o;
#pragma unroll
    for (int q = 0; q < 8; ++q) o[q] = f2bf(acc[q]);
    *(u16x8*)(out + (long)n * H + l * 8) = o;
}

// ---------------- first linear (K = 4), bf16 out ----------------

__global__ void k_lin0(const float* __restrict__ a4, const float* __restrict__ w,
                       const float* __restrict__ b, u16* __restrict__ out) {
    long i = (long)blockIdx.x * blockDim.x + threadIdx.x;   // over NN*100
    if (i >= (long)NN * 100) return;
    int n = (int)(i / 100), q = (int)(i - (long)n * 100);
    int j0 = q * 4;
    float4 av = ((const float4*)a4)[n];
    u16x4 o;
#pragma unroll
    for (int jj = 0; jj < 4; ++jj) {
        float4 wv = ((const float4*)w)[j0 + jj];
        float s = fmaf(av.x, wv.x, fmaf(av.y, wv.y, fmaf(av.z, wv.z, av.w * wv.w)));
        o[jj] = f2bf(s + b[j0 + jj]);
    }
    *(u16x4*)(out + (long)n * H + j0) = o;
}

// ---------------- BN stats over bf16 buffer (after lin0 only) ----------------

__global__ __launch_bounds__(256) void k_statsv(const u16* __restrict__ z,
                                                float* __restrict__ stats) {
    __shared__ float ls[800];
    int t = threadIdx.x;
    for (int i = t; i < 800; i += 256) ls[i] = 0.f;
    __syncthreads();
    if (t < 250) {
        int sub = t / 50, seg = t % 50;
        float s[8] = {0, 0, 0, 0, 0, 0, 0, 0};
        float q[8] = {0, 0, 0, 0, 0, 0, 0, 0};
        for (int r = blockIdx.x * 5 + sub; r < NN; r += gridDim.x * 5) {
            u16x8 v = *(const u16x8*)(z + (long)r * H + seg * 8);
#pragma unroll
            for (int j = 0; j < 8; ++j) {
                float f = bf2f(v[j]);
                s[j] += f; q[j] += f * f;
            }
        }
#pragma unroll
        for (int j = 0; j < 8; ++j) {
            atomicAdd(&ls[seg * 8 + j], s[j]);
            atomicAdd(&ls[400 + seg * 8 + j], q[j]);
        }
    }
    __syncthreads();
    for (int i = t; i < 800; i += 256) atomicAdd(&stats[i], ls[i]);
}

__global__ void k_finalize(float* __restrict__ stats, const float* __restrict__ g,
                           const float* __restrict__ be, float* __restrict__ scale,
                           float* __restrict__ shift) {
    int j = blockIdx.x * blockDim.x + threadIdx.x;
    if (j >= H) return;
    float m = stats[j] / NN;
    float v = stats[H + j] / NN - m * m;
    v = fmaxf(v, 0.f);
    float rs = rsqrtf(v + EPS);
    float sc = g[j] * rs;
    scale[j] = sc;
    shift[j] = be[j] - m * sc;
    stats[j] = 0.f;          // self-clean for next use
    stats[H + j] = 0.f;
}

// ---------------- MFMA GEMM, W-stationary, no barriers in K-loop ----------------
// out[n][c] = sum_j f(A[n][j]) * W[c][j] + bias[c]
// TRANS: f = relu(a*scale+shift). STATS: fused column stats. POOL: fused graph pooling.
// W band (80 cols x 400 K, bf16, 66KB) staged to LDS once; A fragments loaded
// per-lane from global (16B dwordx4), software-pipelined; zero K-loop barriers.
// Grid: 1-D, 391 panels x 5 bands, bijective XCD swizzle (m204) so a panel's
// 5 bands share one XCD's L2.

template <bool TRANS, bool STATS, bool POOL>
__global__ __launch_bounds__(256) void gemm_mfma(const u16* __restrict__ A,
                                                 const u16* __restrict__ W,
                                                 const float* __restrict__ bias,
                                                 const float* __restrict__ scale,
                                                 const float* __restrict__ shift,
                                                 u16* __restrict__ out,
                                                 float* __restrict__ stats,
                                                 const int* __restrict__ batch,
                                                 float* __restrict__ pools,
                                                 int poolOff, int M) {
    constexpr int LDK = 424;             // u16 per LDS B row (416 data + 8 pad)
    __shared__ u16 Bs[80 * LDK];         // 67,840 B
    __shared__ float sst[160];
    __shared__ float pacc[6 * 80];
    __shared__ int sgmm[2];

    const int t = threadIdx.x;
    // bijective XCD swizzle: nwg = 1955 = 8*244 + 3
    const int nwg = gridDim.x;
    const int q8 = nwg >> 3, r8 = nwg & 7;
    const int xcd = blockIdx.x & 7, jj = blockIdx.x >> 3;
    const int wgid = (xcd < r8 ? xcd * (q8 + 1) : r8 * (q8 + 1) + (xcd - r8) * q8) + jj;
    const int bm = (wgid / 5) * 128;
    const int bn = (wgid % 5) * 80;
    const int w = t >> 6, l = t & 63;

    // ---- stage W band into LDS (once) ----
    for (int seg = t; seg < 80 * 52; seg += 256) {
        int row = seg / 52, kq = seg % 52;
        int k = kq * 8;
        u16x8 v = {0, 0, 0, 0, 0, 0, 0, 0};
        if (k < 400) v = *(const u16x8*)(W + (long)(bn + row) * 400 + k);
        *(u16x8*)&Bs[row * LDK + k] = v;
    }
    if (STATS && t < 160) sst[t] = 0.f;
    if (POOL) {
        if (t == 0) {
            sgmm[0] = batch[min(bm, M - 1)];
            sgmm[1] = batch[min(bm + 127, M - 1)];
        }
        for (int i = t; i < 480; i += 256) pacc[i] = 0.f;
    }
    __syncthreads();

    f32x4 acc[2][5];
#pragma unroll
    for (int i = 0; i < 2; ++i)
#pragma unroll
        for (int c = 0; c < 5; ++c)
            acc[i][c] = (f32x4){0.f, 0.f, 0.f, 0.f};

    const int r16 = l & 15;              // row within 16-group
    const int kc  = (l >> 4) * 8;        // lane k-chunk offset within 32
    const long rowA0 = (long)(bm + w * 32 + r16);
    const long rowA1 = rowA0 + 16;
    const bool ok0 = rowA0 < M, ok1 = rowA1 < M;

    auto rawA = [&](long row, bool ok, int s) -> u16x8 {
        u16x8 v = {0, 0, 0, 0, 0, 0, 0, 0};
        int k = s * 32 + kc;
        if (ok && k < 400) v = *(const u16x8*)(A + row * 400 + k);
        return v;
    };
    auto xform = [&](u16x8 v, int s) -> bf16x8 {
        if (TRANS) {
            int k = s * 32 + kc;
            if (k < 400) {
                float4 sc0 = *(const float4*)(scale + k);
                float4 sc1 = *(const float4*)(scale + k + 4);
                float4 sh0 = *(const float4*)(shift + k);
                float4 sh1 = *(const float4*)(shift + k + 4);
                u16x8 o;
                o[0] = f2bf(fmaxf(fmaf(bf2f(v[0]), sc0.x, sh0.x), 0.f));
                o[1] = f2bf(fmaxf(fmaf(bf2f(v[1]), sc0.y, sh0.y), 0.f));
                o[2] = f2bf(fmaxf(fmaf(bf2f(v[2]), sc0.z, sh0.z), 0.f));
                o[3] = f2bf(fmaxf(fmaf(bf2f(v[3]), sc0.w, sh0.w), 0.f));
                o[4] = f2bf(fmaxf(fmaf(bf2f(v[4]), sc1.x, sh1.x), 0.f));
                o[5] = f2bf(fmaxf(fmaf(bf2f(v[5]), sc1.y, sh1.y), 0.f));
                o[6] = f2bf(fmaxf(fmaf(bf2f(v[6]), sc1.z, sh1.z), 0.f));
                o[7] = f2bf(fmaxf(fmaf(bf2f(v[7]), sc1.w, sh1.w), 0.f));
                return (bf16x8)o;
            }
        }
        return (bf16x8)v;
    };

    constexpr int NK = 13;
    u16x8 cur0 = rawA(rowA0, ok0, 0);
    u16x8 cur1 = rawA(rowA1, ok1, 0);
#pragma unroll 1
    for (int s = 0; s < NK; ++s) {
        u16x8 nx0 = cur0, nx1 = cur1;
        if (s + 1 < NK) {
            nx0 = rawA(rowA0, ok0, s + 1);
            nx1 = rawA(rowA1, ok1, s + 1);
        }
        bf16x8 fa0 = xform(cur0, s);
        bf16x8 fa1 = xform(cur1, s);
        const u16* bb = &Bs[r16 * LDK + s * 32 + kc];
#pragma unroll
        for (int c = 0; c < 5; ++c) {
            bf16x8 fb = *(const bf16x8*)(bb + c * 16 * LDK);
            acc[0][c] = __builtin_amdgcn_mfma_f32_16x16x32_bf16(fa0, fb, acc[0][c], 0, 0, 0);
            acc[1][c] = __builtin_amdgcn_mfma_f32_16x16x32_bf16(fa1, fb, acc[1][c], 0, 0, 0);
        }
        cur0 = nx0; cur1 = nx1;
    }

    int span = 0;
    int grow[2][4];
    if (POOL) {
        span = sgmm[1] - sgmm[0] + 1;
#pragma unroll
        for (int i = 0; i < 2; ++i) {
            int rbase = bm + w * 32 + i * 16 + (l >> 4) * 4;
#pragma unroll
            for (int r = 0; r < 4; ++r)
                grow[i][r] = (rbase + r < M) ? batch[rbase + r] : -1;
        }
    }

    // epilogue: C/D layout col=lane&15, row=(lane>>4)*4+reg
    float ssum[5], sqq[5];
#pragma unroll
    for (int c = 0; c < 5; ++c) { ssum[c] = 0.f; sqq[c] = 0.f; }
#pragma unroll
    for (int i = 0; i < 2; ++i) {
        const int rbase = bm + w * 32 + i * 16 + (l >> 4) * 4;
#pragma unroll
        for (int c = 0; c < 5; ++c) {
            const int col = bn + c * 16 + (l & 15);
            const float bv = bias[col];
#pragma unroll
            for (int r = 0; r < 4; ++r) {
                const int row = rbase + r;
                if (row < M) {
                    float z = acc[i][c][r] + bv;
                    out[(long)row * H + col] = f2bf(z);
                    if (STATS) { ssum[c] += z; sqq[c] += z * z; }
                    if (POOL) {
                        int g = grow[i][r];
                        if (span <= 6)
                            atomicAdd(&pacc[(g - sgmm[0]) * 80 + c * 16 + (l & 15)], z);
                        else
                            atomicAdd(&pools[(long)g * 1200 + poolOff + col], z);
                    }
                }
            }
        }
    }
    if (STATS) {
#pragma unroll
        for (int c = 0; c < 5; ++c) {
            ssum[c] += __shfl_xor(ssum[c], 16); ssum[c] += __shfl_xor(ssum[c], 32);
            sqq[c]  += __shfl_xor(sqq[c], 16);  sqq[c]  += __shfl_xor(sqq[c], 32);
        }
        if (l < 16) {
#pragma unroll
            for (int c = 0; c < 5; ++c) {
                atomicAdd(&sst[c * 16 + l], ssum[c]);
                atomicAdd(&sst[80 + c * 16 + l], sqq[c]);
            }
        }
        __syncthreads();
        if (t < 80)       atomicAdd(&stats[bn + t], sst[t]);
        else if (t < 160) atomicAdd(&stats[H + bn + (t - 80)], sst[t]);
    }
    if (POOL) {
        __syncthreads();
        if (span <= 6) {
            int nsp = span * 80;
            for (int i = t; i < nsp; i += 256) {
                atomicAdd(&pools[(long)(sgmm[0] + i / 80) * 1200 + poolOff + bn + (i % 80)],
                          pacc[i]);
            }
        }
    }
}

// ---------------- readout ----------------

__global__ __launch_bounds__(256) void k_lin1(const float* __restrict__ pools,
                                              const float* __restrict__ w1,
                                              const float* __restrict__ b1,
                                              float* __restrict__ zz) {
    __shared__ __align__(16) float xg[1200];
    int band = blockIdx.x, g = blockIdx.y, t = threadIdx.x;
    for (int i = t; i < 1200; i += 256) xg[i] = pools[(long)g * 1200 + i];
    __syncthreads();
    if (t < 240) {
        int j = band * 120 + (t >> 1);
        int kh = t & 1;
        const float4* wr = (const float4*)(w1 + (long)j * 1200 + kh * 600);
        const float4* xr = (const float4*)(xg + kh * 600);
        float s = 0.f;
        for (int q = 0; q < 150; ++q) {
            float4 a = xr[q], b = wr[q];
            s = fmaf(a.x, b.x, s); s = fmaf(a.y, b.y, s);
            s = fmaf(a.z, b.z, s); s = fmaf(a.w, b.w, s);
        }
        s += __shfl_xor(s, 1);
        if (!kh) zz[(long)g * 600 + j] = fmaxf(s + b1[j], 0.f);
    }
}

__global__ __launch_bounds__(64) void k_lin2(const float* __restrict__ zz,
                                             const float* __restrict__ w2,
                                             const float* __restrict__ b2,
                                             float* __restrict__ out) {
    int g = blockIdx.x;
    int l = threadIdx.x;
    float p[NC];
#pragma unroll
    for (int c = 0; c < NC; ++c) p[c] = 0.f;
    for (int k = l; k < 600; k += 64) {
        float zv = zz[(long)g * 600 + k];
#pragma unroll
        for (int c = 0; c < NC; ++c) p[c] = fmaf(zv, w2[c * 600 + k], p[c]);
    }
#pragma unroll
    for (int c = 0; c < NC; ++c)
#pragma unroll
        for (int o = 32; o; o >>= 1) p[c] += __shfl_xor(p[c], o);
    if (l == 0) {
        float lg[NC];
        float mx = -1e30f;
#pragma unroll
        for (int c = 0; c < NC; ++c) { lg[c] = p[c] + b2[c]; mx = fmaxf(mx, lg[c]); }
        float se = 0.f;
#pragma unroll
        for (int c = 0; c < NC; ++c) se += expf(lg[c] - mx);
        float lse = logf(se);
#pragma unroll
        for (int c = 0; c < NC; ++c) out[(long)g * NC + c] = lg[c] - mx - lse;
    }
}

// ---------------- launch ----------------

extern "C" void kernel_launch(void* const* d_in, const int* in_sizes, int n_in,
                              void* d_out, int out_size, void* d_ws, size_t ws_size,
                              hipStream_t stream) {
    const float* x      = (const float*)d_in[0];
    const int*   ei     = (const int*)d_in[1];
    const int*   batch  = (const int*)d_in[2];
    const float* c0_w1  = (const float*)d_in[4];
    const float* c0_b1  = (const float*)d_in[5];
    const float* c0_g1  = (const float*)d_in[6];
    const float* c0_be1 = (const float*)d_in[7];
    const float* c0_w2  = (const float*)d_in[8];
    const float* c0_b2  = (const float*)d_in[9];
    const float* c0_g2  = (const float*)d_in[10];
    const float* c0_be2 = (const float*)d_in[11];
    const float* c0_w3  = (const float*)d_in[12];
    const float* c0_b3  = (const float*)d_in[13];
    const float* cw1    = (const float*)d_in[14];
    const float* cb1    = (const float*)d_in[15];
    const float* cg1    = (const float*)d_in[16];
    const float* cbe1   = (const float*)d_in[17];
    const float* cw2    = (const float*)d_in[18];
    const float* cb2    = (const float*)d_in[19];
    const float* cg2    = (const float*)d_in[20];
    const float* cbe2   = (const float*)d_in[21];
    const float* cw3    = (const float*)d_in[22];
    const float* cb3    = (const float*)d_in[23];
    const float* lin1_w = (const float*)d_in[24];
    const float* lin1_b = (const float*)d_in[25];
    const float* lin2_w = (const float*)d_in[26];
    const float* lin2_b = (const float*)d_in[27];

    const int* src = ei;
    const int* dst = ei + NE;

    char* ws = (char*)d_ws;
    size_t off = 0;
    auto alloc = [&](size_t bytes) {
        void* p = ws + off;
        off += (bytes + 255) & ~(size_t)255;
        return p;
    };
    u16*   bufh  = (u16*)alloc((size_t)NN * H * 2);
    u16*   bufa  = (u16*)alloc((size_t)NN * H * 2);
    float* agg0  = (float*)alloc((size_t)NN * 4 * 4);
    float* stats = (float*)alloc(2 * H * 4);
    float* scale = (float*)alloc(H * 4);
    float* shift = (float*)alloc(H * 4);
    float* pools = (float*)alloc((size_t)NG * 3 * H * 4);
    float* zz    = (float*)alloc((size_t)NG * 600 * 4);
    // contiguous bf16 weight block: w2b_0 | w3b_0 | w1b | w2b | w3b
    u16*   w2b_0 = (u16*)alloc((size_t)8 * H * H * 2);
    u16*   w3b_0 = w2b_0 + (size_t)H * H;
    u16*   w1b   = w3b_0 + (size_t)H * H;
    u16*   w2b   = w1b + (size_t)2 * H * H;
    u16*   w3b   = w2b + (size_t)2 * H * H;
    int*   deg   = (int*)alloc((size_t)NN * 4);
    int*   rowp  = (int*)alloc((size_t)(NN + 1) * 4);
    int*   cur   = (int*)alloc((size_t)NN * 4);
    int*   csrc  = (int*)alloc((size_t)NE * 4);
    int*   part  = (int*)alloc((size_t)NN * 4);
    int*   btot  = (int*)alloc((size_t)NB1 * 4);

    hipMemsetAsync(deg, 0, (size_t)NN * 4, stream);
    hipMemsetAsync(stats, 0, 2 * H * 4, stream);
    hipMemsetAsync(pools, 0, (size_t)NG * 3 * H * 4, stream);

    k_cvtw_all<<<(8 * H * H / 4 + 255) / 256, 256, 0, stream>>>(c0_w2, c0_w3, cw1, cw2, cw3,
                                                                w2b_0);

    // CSR build
    k_count<<<(NE + 255) / 256, 256, 0, stream>>>(dst, deg);
    k_scan1<<<NB1, 256, 0, stream>>>(deg, part, btot);
    k_scan2<<<1, 256, 0, stream>>>(btot);
    k_scan3<<<NB1, 256, 0, stream>>>(part, btot, deg, rowp, cur);
    k_scatter<<<(NE + 255) / 256, 256, 0, stream>>>(src, dst, cur, csrc);

    const int ngemm = ((NN + 127) / 128) * 5;   // 1955 blocks

    // layer 0
    k_agg0<<<(NN + 255) / 256, 256, 0, stream>>>(x, rowp, csrc, agg0);
    k_lin0<<<(int)(((long)NN * 100 + 255) / 256), 256, 0, stream>>>(agg0, c0_w1, c0_b1, bufh);
    k_statsv<<<96, 256, 0, stream>>>(bufh, stats);
    k_finalize<<<2, 256, 0, stream>>>(stats, c0_g1, c0_be1, scale, shift);
    gemm_mfma<true, true, false><<<ngemm, 256, 0, stream>>>(bufh, w2b_0, c0_b2, scale, shift,
                                                            bufa, stats, nullptr, nullptr, 0, NN);
    k_finalize<<<2, 256, 0, stream>>>(stats, c0_g2, c0_be2, scale, shift);
    gemm_mfma<true, false, true><<<ngemm, 256, 0, stream>>>(bufa, w3b_0, c0_b3, scale, shift,
                                                            bufh, nullptr, batch, pools, 0, NN);

    // layers 1..2
    for (int l = 0; l < 2; ++l) {
        k_aggH<<<(NN + 3) / 4, 256, 0, stream>>>(bufh, rowp, csrc, bufa);
        gemm_mfma<false, true, false><<<ngemm, 256, 0, stream>>>(bufa, w1b + (size_t)l * H * H,
                                                                 cb1 + l * H, nullptr, nullptr,
                                                                 bufh, stats, nullptr, nullptr,
                                                                 0, NN);
        k_finalize<<<2, 256, 0, stream>>>(stats, cg1 + l * H, cbe1 + l * H, scale, shift);
        gemm_mfma<true, true, false><<<ngemm, 256, 0, stream>>>(bufh, w2b + (size_t)l * H * H,
                                                                cb2 + l * H, scale, shift,
                                                                bufa, stats, nullptr, nullptr,
                                                                0, NN);
        k_finalize<<<2, 256, 0, stream>>>(stats, cg2 + l * H, cbe2 + l * H, scale, shift);
        gemm_mfma<true, false, true><<<ngemm, 256, 0, stream>>>(bufa, w3b + (size_t)l * H * H,
                                                                cb3 + l * H, scale, shift,
                                                                bufh, nullptr, batch, pools,
                                                                (l + 1) * H, NN);
    }

    // readout
    dim3 gl1(5, NG);
    k_lin1<<<gl1, 256, 0, stream>>>(pools, lin1_w, lin1_b, zz);
    k_lin2<<<NG, 64, 0, stream>>>(zz, lin2_w, lin2_b, (float*)d_out);
}

// Round 6
// 1026.118 us; speedup vs baseline: 1.1903x; 1.1903x over previous
//
#include <hip/hip_runtime.h>
#include <hip/hip_bf16.h>
#include <math.h>
#include <cstdint>

static constexpr int NN = 50000;   // nodes
static constexpr int NE = 400000;  // edges
static constexpr int H  = 400;     // hidden dim
static constexpr int NG = 128;     // graphs
static constexpr int NC = 10;      // classes
static constexpr float EPS = 1e-5f;
static constexpr int NB1 = (NN + 255) / 256;   // 196 scan blocks
static constexpr int KP  = 416;                // padded K for weights

typedef unsigned short u16;
typedef __attribute__((ext_vector_type(8))) unsigned short u16x8;
typedef __attribute__((ext_vector_type(4))) unsigned short u16x4;
typedef __attribute__((ext_vector_type(8))) short bf16x8;
typedef __attribute__((ext_vector_type(4))) float f32x4;

__device__ __forceinline__ float bf2f(u16 u) {
    return __uint_as_float(((uint32_t)u) << 16);
}
__device__ __forceinline__ u16 f2bf(float f) {
    uint32_t u = __float_as_uint(f);
    return (u16)((u + 0x7FFFu + ((u >> 16) & 1u)) >> 16);
}
__device__ __forceinline__ void gload_lds16(const void* g, void* lds) {
    __builtin_amdgcn_global_load_lds((const __attribute__((address_space(1))) void*)g,
                                     (__attribute__((address_space(3))) void*)lds, 16, 0, 0);
}

// ---------------- CSR build ----------------

__global__ void k_count(const int* __restrict__ dst, int* __restrict__ deg) {
    int e = blockIdx.x * blockDim.x + threadIdx.x;
    if (e < NE) atomicAdd(&deg[dst[e]], 1);
}

__global__ __launch_bounds__(256) void k_scan1(const int* __restrict__ deg,
                                               int* __restrict__ part,
                                               int* __restrict__ btot) {
    __shared__ int sd[256];
    int t = threadIdx.x;
    int i = blockIdx.x * 256 + t;
    int v = (i < NN) ? deg[i] : 0;
    sd[t] = v;
    __syncthreads();
#pragma unroll
    for (int off = 1; off < 256; off <<= 1) {
        int x = (t >= off) ? sd[t - off] : 0;
        __syncthreads();
        sd[t] += x;
        __syncthreads();
    }
    if (i < NN) part[i] = sd[t];
    if (t == 255) btot[blockIdx.x] = sd[255];
}

__global__ __launch_bounds__(256) void k_scan2(int* __restrict__ btot) {
    __shared__ int sd[256];
    int t = threadIdx.x;
    int v = (t < NB1) ? btot[t] : 0;
    sd[t] = v;
    __syncthreads();
#pragma unroll
    for (int off = 1; off < 256; off <<= 1) {
        int x = (t >= off) ? sd[t - off] : 0;
        __syncthreads();
        sd[t] += x;
        __syncthreads();
    }
    if (t < NB1) btot[t] = sd[t];
}

__global__ __launch_bounds__(256) void k_scan3(const int* __restrict__ part,
                                               const int* __restrict__ btot,
                                               const int* __restrict__ deg,
                                               int* __restrict__ rowp,
                                               int* __restrict__ cur) {
    int i = blockIdx.x * 256 + threadIdx.x;
    if (i < NN) {
        int s = part[i] + (blockIdx.x ? btot[blockIdx.x - 1] : 0);
        rowp[i + 1] = s;
        cur[i] = s - deg[i];
    }
    if (i == 0) rowp[0] = 0;
}

__global__ void k_scatter(const int* __restrict__ src, const int* __restrict__ dst,
                          int* __restrict__ cur, int* __restrict__ csrc) {
    int e = blockIdx.x * blockDim.x + threadIdx.x;
    if (e < NE) {
        int d = dst[e];
        int p = atomicAdd(&cur[d], 1);
        csrc[p] = src[e];
    }
}

// ---------------- weights fp32 -> bf16, padded to [8*400][416] (zeros k>=400) ----------------

__global__ void k_cvtw_all(const float* __restrict__ s0, const float* __restrict__ s1,
                           const float* __restrict__ s2, const float* __restrict__ s3,
                           const float* __restrict__ s4, u16* __restrict__ dst) {
    int i = blockIdx.x * blockDim.x + threadIdx.x;   // over 8*400*52
    if (i >= 8 * 400 * 52) return;
    int rc = i / 52;              // 0..3199 global row
    int c8 = (i % 52) * 8;
    u16x8 o = {0, 0, 0, 0, 0, 0, 0, 0};
    if (c8 < 400) {
        int mat = rc / 400, row = rc % 400;
        const float* s;
        if (mat == 0)      s = s0 + (long)row * 400;
        else if (mat == 1) s = s1 + (long)row * 400;
        else if (mat < 4)  s = s2 + (long)(mat - 2) * 400 * 400 + (long)row * 400;
        else if (mat < 6)  s = s3 + (long)(mat - 4) * 400 * 400 + (long)row * 400;
        else               s = s4 + (long)(mat - 6) * 400 * 400 + (long)row * 400;
        float4 a = *(const float4*)(s + c8);
        float4 b = *(const float4*)(s + c8 + 4);
        o[0] = f2bf(a.x); o[1] = f2bf(a.y); o[2] = f2bf(a.z); o[3] = f2bf(a.w);
        o[4] = f2bf(b.x); o[5] = f2bf(b.y); o[6] = f2bf(b.z); o[7] = f2bf(b.w);
    }
    *(u16x8*)(dst + (long)rc * KP + c8) = o;
}

// ---------------- aggregation ----------------

__global__ void k_agg0(const float* __restrict__ x, const int* __restrict__ rowp,
                       const int* __restrict__ csrc, float* __restrict__ out) {
    int n = blockIdx.x * blockDim.x + threadIdx.x;
    if (n >= NN) return;
    float4 acc = make_float4(0.f, 0.f, 0.f, 0.f);
    int b = rowp[n], e = rowp[n + 1];
    for (int p = b; p < e; ++p) {
        float4 v = ((const float4*)x)[csrc[p]];
        acc.x += v.x; acc.y += v.y; acc.z += v.z; acc.w += v.w;
    }
    ((float4*)out)[n] = acc;
}

// one wave per node; lanes 0..49 each own 8 contiguous features
__global__ __launch_bounds__(256) void k_aggH(const u16* __restrict__ h,
                                              const int* __restrict__ rowp,
                                              const int* __restrict__ csrc,
                                              u16* __restrict__ out) {
    int n = (blockIdx.x << 2) + (threadIdx.x >> 6);
    if (n >= NN) return;
    int l = threadIdx.x & 63;
    if (l >= 50) return;
    int b = rowp[n], e = rowp[n + 1];
    float acc[8] = {0.f, 0.f, 0.f, 0.f, 0.f, 0.f, 0.f, 0.f};
    for (int p = b; p < e; ++p) {
        const u16* r = h + (long)csrc[p] * H + l * 8;
        u16x8 v = *(const u16x8*)r;
#pragma unroll
        for (int q = 0; q < 8; ++q) acc[q] += bf2f(v[q]);
    }
    u16x8 o;
#pragma unroll
    for (int q = 0; q < 8; ++q) o[q] = f2bf(acc[q]);
    *(u16x8*)(out + (long)n * H + l * 8) = o;
}

// ---------------- first linear (K = 4), bf16 out ----------------

__global__ void k_lin0(const float* __restrict__ a4, const float* __restrict__ w,
                       const float* __restrict__ b, u16* __restrict__ out) {
    long i = (long)blockIdx.x * blockDim.x + threadIdx.x;   // over NN*100
    if (i >= (long)NN * 100) return;
    int n = (int)(i / 100), q = (int)(i - (long)n * 100);
    int j0 = q * 4;
    float4 av = ((const float4*)a4)[n];
    u16x4 o;
#pragma unroll
    for (int jj = 0; jj < 4; ++jj) {
        float4 wv = ((const float4*)w)[j0 + jj];
        float s = fmaf(av.x, wv.x, fmaf(av.y, wv.y, fmaf(av.z, wv.z, av.w * wv.w)));
        o[jj] = f2bf(s + b[j0 + jj]);
    }
    *(u16x4*)(out + (long)n * H + j0) = o;
}

// ---------------- BN stats over bf16 buffer (after lin0 only) ----------------

__global__ __launch_bounds__(256) void k_statsv(const u16* __restrict__ z,
                                                float* __restrict__ stats) {
    __shared__ float ls[800];
    int t = threadIdx.x;
    for (int i = t; i < 800; i += 256) ls[i] = 0.f;
    __syncthreads();
    if (t < 250) {
        int sub = t / 50, seg = t % 50;
        float s[8] = {0, 0, 0, 0, 0, 0, 0, 0};
        float q[8] = {0, 0, 0, 0, 0, 0, 0, 0};
        for (int r = blockIdx.x * 5 + sub; r < NN; r += gridDim.x * 5) {
            u16x8 v = *(const u16x8*)(z + (long)r * H + seg * 8);
#pragma unroll
            for (int j = 0; j < 8; ++j) {
                float f = bf2f(v[j]);
                s[j] += f; q[j] += f * f;
            }
        }
#pragma unroll
        for (int j = 0; j < 8; ++j) {
            atomicAdd(&ls[seg * 8 + j], s[j]);
            atomicAdd(&ls[400 + seg * 8 + j], q[j]);
        }
    }
    __syncthreads();
    for (int i = t; i < 800; i += 256) atomicAdd(&stats[i], ls[i]);
}

__global__ void k_finalize(float* __restrict__ stats, const float* __restrict__ g,
                           const float* __restrict__ be, float* __restrict__ scale,
                           float* __restrict__ shift) {
    int j = blockIdx.x * blockDim.x + threadIdx.x;
    if (j >= H) return;
    float m = stats[j] / NN;
    float v = stats[H + j] / NN - m * m;
    v = fmaxf(v, 0.f);
    float rs = rsqrtf(v + EPS);
    float sc = g[j] * rs;
    scale[j] = sc;
    shift[j] = be[j] - m * sc;
    stats[j] = 0.f;          // self-clean for next use
    stats[H + j] = 0.f;
}

// ---------------- BN+ReLU elementwise, in place ----------------

__global__ __launch_bounds__(256) void k_bnrelu(u16* __restrict__ z,
                                                const float* __restrict__ scale,
                                                const float* __restrict__ shift) {
    long i = (long)blockIdx.x * 256 + threadIdx.x;   // over NN*50
    if (i >= (long)NN * 50) return;
    int c8 = (int)(i % 50) * 8;
    u16* p = z + i * 8;
    u16x8 v = *(const u16x8*)p;
    float4 s0 = *(const float4*)(scale + c8);
    float4 s1 = *(const float4*)(scale + c8 + 4);
    float4 h0 = *(const float4*)(shift + c8);
    float4 h1 = *(const float4*)(shift + c8 + 4);
    u16x8 o;
    o[0] = f2bf(fmaxf(fmaf(bf2f(v[0]), s0.x, h0.x), 0.f));
    o[1] = f2bf(fmaxf(fmaf(bf2f(v[1]), s0.y, h0.y), 0.f));
    o[2] = f2bf(fmaxf(fmaf(bf2f(v[2]), s0.z, h0.z), 0.f));
    o[3] = f2bf(fmaxf(fmaf(bf2f(v[3]), s0.w, h0.w), 0.f));
    o[4] = f2bf(fmaxf(fmaf(bf2f(v[4]), s1.x, h1.x), 0.f));
    o[5] = f2bf(fmaxf(fmaf(bf2f(v[5]), s1.y, h1.y), 0.f));
    o[6] = f2bf(fmaxf(fmaf(bf2f(v[6]), s1.z, h1.z), 0.f));
    o[7] = f2bf(fmaxf(fmaf(bf2f(v[7]), s1.w, h1.w), 0.f));
    *(u16x8*)p = o;
}

// ---------------- MFMA GEMM: pure bf16, global_load_lds double-buffered ----------------
// out[n][c] = sum_j A[n][j] * Wp[c][j] + bias[c];  A: M x 400, Wp: 400 x 416 (zero-pad)
// Tile 128x80, BK=32, 4 waves. LDS linear [row][32] u16 (64 B rows): the wave's
// b128 reads cover a full 16-row x 64 B region -> uniform 8 accesses/bank (BW floor).
// STATS: fused column sum/sumsq. POOL: fused per-graph column sums (batch sorted).

template <bool STATS, bool POOL>
__global__ __launch_bounds__(256) void gemm_mfma(const u16* __restrict__ A,
                                                 const u16* __restrict__ Wp,
                                                 const float* __restrict__ bias,
                                                 u16* __restrict__ out,
                                                 float* __restrict__ stats,
                                                 const int* __restrict__ batch,
                                                 float* __restrict__ pools,
                                                 int poolOff, int M) {
    __shared__ u16 As[2][128 * 32];
    __shared__ u16 Bs[2][80 * 32];
    __shared__ float sst[160];
    __shared__ float pacc[6 * 80];
    __shared__ int sgmm[2];

    const int t = threadIdx.x;
    // bijective XCD swizzle (nwg = 1955, not divisible by 8)
    const int nwg = gridDim.x;
    const int q8 = nwg >> 3, r8 = nwg & 7;
    const int xcd = blockIdx.x & 7, jj = blockIdx.x >> 3;
    const int wgid = (xcd < r8 ? xcd * (q8 + 1) : r8 * (q8 + 1) + (xcd - r8) * q8) + jj;
    const int bm = (wgid / 5) * 128;
    const int bn = (wgid % 5) * 80;
    const int w = t >> 6, l = t & 63;

    const int lrow = l >> 2;        // 0..15 within a 1 KB segment
    const int lk   = (l & 3) * 8;   // k-chunk offset (u16)

    auto stageAll = [&](int b, int k0) {
        for (int seg = w; seg < 13; seg += 4) {
            if (seg < 8) {
                long grow = (long)bm + seg * 16 + lrow;
                if (grow > M - 1) grow = M - 1;
                gload_lds16(A + grow * 400 + k0 + lk, &As[b][seg * 512]);
            } else {
                int row = (seg - 8) * 16 + lrow;
                gload_lds16(Wp + (long)(bn + row) * KP + k0 + lk, &Bs[b][(seg - 8) * 512]);
            }
        }
    };

    f32x4 acc[2][5];
#pragma unroll
    for (int i = 0; i < 2; ++i)
#pragma unroll
        for (int c = 0; c < 5; ++c)
            acc[i][c] = (f32x4){0.f, 0.f, 0.f, 0.f};

    const int r16 = l & 15;
    const int kc  = (l >> 4) * 8;

    auto compute = [&](int b) {
        const u16* ab = &As[b][(w * 32 + r16) * 32 + kc];
        const u16* bb = &Bs[b][r16 * 32 + kc];
        bf16x8 fa0 = *(const bf16x8*)ab;
        bf16x8 fa1 = *(const bf16x8*)(ab + 16 * 32);
#pragma unroll
        for (int c = 0; c < 5; ++c) {
            bf16x8 fb = *(const bf16x8*)(bb + c * 16 * 32);
            acc[0][c] = __builtin_amdgcn_mfma_f32_16x16x32_bf16(fa0, fb, acc[0][c], 0, 0, 0);
            acc[1][c] = __builtin_amdgcn_mfma_f32_16x16x32_bf16(fa1, fb, acc[1][c], 0, 0, 0);
        }
    };

    stageAll(0, 0);
    if (STATS && t < 160) sst[t] = 0.f;
    if (POOL) {
        if (t == 0) {
            sgmm[0] = batch[min(bm, M - 1)];
            sgmm[1] = batch[min(bm + 127, M - 1)];
        }
        for (int i = t; i < 480; i += 256) pacc[i] = 0.f;
    }
    __syncthreads();

    constexpr int NK = 13;   // ceil(400/32); K-tail: A garbage x W zero-pad = 0
#pragma unroll 1
    for (int s = 0; s < NK; ++s) {
        if (s + 1 < NK) stageAll((s + 1) & 1, (s + 1) * 32);
        compute(s & 1);
        __syncthreads();
    }

    int span = 0;
    int grow[2][4];
    if (POOL) {
        span = sgmm[1] - sgmm[0] + 1;
#pragma unroll
        for (int i = 0; i < 2; ++i) {
            int rbase = bm + w * 32 + i * 16 + (l >> 4) * 4;
#pragma unroll
            for (int r = 0; r < 4; ++r)
                grow[i][r] = (rbase + r < M) ? batch[rbase + r] : -1;
        }
    }

    // epilogue: C/D layout col=lane&15, row=(lane>>4)*4+reg
    float ssum[5], sqq[5];
#pragma unroll
    for (int c = 0; c < 5; ++c) { ssum[c] = 0.f; sqq[c] = 0.f; }
#pragma unroll
    for (int i = 0; i < 2; ++i) {
        const int rbase = bm + w * 32 + i * 16 + (l >> 4) * 4;
#pragma unroll
        for (int c = 0; c < 5; ++c) {
            const int col = bn + c * 16 + (l & 15);
            const float bv = bias[col];
#pragma unroll
            for (int r = 0; r < 4; ++r) {
                const int row = rbase + r;
                if (row < M) {
                    float z = acc[i][c][r] + bv;
                    out[(long)row * H + col] = f2bf(z);
                    if (STATS) { ssum[c] += z; sqq[c] += z * z; }
                    if (POOL) {
                        int g = grow[i][r];
                        if (span <= 6)
                            atomicAdd(&pacc[(g - sgmm[0]) * 80 + c * 16 + (l & 15)], z);
                        else
                            atomicAdd(&pools[(long)g * 1200 + poolOff + col], z);
                    }
                }
            }
        }
    }
    if (STATS) {
#pragma unroll
        for (int c = 0; c < 5; ++c) {
            ssum[c] += __shfl_xor(ssum[c], 16); ssum[c] += __shfl_xor(ssum[c], 32);
            sqq[c]  += __shfl_xor(sqq[c], 16);  sqq[c]  += __shfl_xor(sqq[c], 32);
        }
        if (l < 16) {
#pragma unroll
            for (int c = 0; c < 5; ++c) {
                atomicAdd(&sst[c * 16 + l], ssum[c]);
                atomicAdd(&sst[80 + c * 16 + l], sqq[c]);
            }
        }
        __syncthreads();
        if (t < 80)       atomicAdd(&stats[bn + t], sst[t]);
        else if (t < 160) atomicAdd(&stats[H + bn + (t - 80)], sst[t]);
    }
    if (POOL) {
        __syncthreads();
        if (span <= 6) {
            int nsp = span * 80;
            for (int i = t; i < nsp; i += 256) {
                atomicAdd(&pools[(long)(sgmm[0] + i / 80) * 1200 + poolOff + bn + (i % 80)],
                          pacc[i]);
            }
        }
    }
}

// ---------------- readout ----------------

__global__ __launch_bounds__(256) void k_lin1(const float* __restrict__ pools,
                                              const float* __restrict__ w1,
                                              const float* __restrict__ b1,
                                              float* __restrict__ zz) {
    __shared__ __align__(16) float xg[1200];
    int band = blockIdx.x, g = blockIdx.y, t = threadIdx.x;
    for (int i = t; i < 1200; i += 256) xg[i] = pools[(long)g * 1200 + i];
    __syncthreads();
    if (t < 240) {
        int j = band * 120 + (t >> 1);
        int kh = t & 1;
        const float4* wr = (const float4*)(w1 + (long)j * 1200 + kh * 600);
        const float4* xr = (const float4*)(xg + kh * 600);
        float s = 0.f;
        for (int q = 0; q < 150; ++q) {
            float4 a = xr[q], b = wr[q];
            s = fmaf(a.x, b.x, s); s = fmaf(a.y, b.y, s);
            s = fmaf(a.z, b.z, s); s = fmaf(a.w, b.w, s);
        }
        s += __shfl_xor(s, 1);
        if (!kh) zz[(long)g * 600 + j] = fmaxf(s + b1[j], 0.f);
    }
}

__global__ __launch_bounds__(64) void k_lin2(const float* __restrict__ zz,
                                             const float* __restrict__ w2,
                                             const float* __restrict__ b2,
                                             float* __restrict__ out) {
    int g = blockIdx.x;
    int l = threadIdx.x;
    float p[NC];
#pragma unroll
    for (int c = 0; c < NC; ++c) p[c] = 0.f;
    for (int k = l; k < 600; k += 64) {
        float zv = zz[(long)g * 600 + k];
#pragma unroll
        for (int c = 0; c < NC; ++c) p[c] = fmaf(zv, w2[c * 600 + k], p[c]);
    }
#pragma unroll
    for (int c = 0; c < NC; ++c)
#pragma unroll
        for (int o = 32; o; o >>= 1) p[c] += __shfl_xor(p[c], o);
    if (l == 0) {
        float lg[NC];
        float mx = -1e30f;
#pragma unroll
        for (int c = 0; c < NC; ++c) { lg[c] = p[c] + b2[c]; mx = fmaxf(mx, lg[c]); }
        float se = 0.f;
#pragma unroll
        for (int c = 0; c < NC; ++c) se += expf(lg[c] - mx);
        float lse = logf(se);
#pragma unroll
        for (int c = 0; c < NC; ++c) out[(long)g * NC + c] = lg[c] - mx - lse;
    }
}

// ---------------- launch ----------------

extern "C" void kernel_launch(void* const* d_in, const int* in_sizes, int n_in,
                              void* d_out, int out_size, void* d_ws, size_t ws_size,
                              hipStream_t stream) {
    const float* x      = (const float*)d_in[0];
    const int*   ei     = (const int*)d_in[1];
    const int*   batch  = (const int*)d_in[2];
    const float* c0_w1  = (const float*)d_in[4];
    const float* c0_b1  = (const float*)d_in[5];
    const float* c0_g1  = (const float*)d_in[6];
    const float* c0_be1 = (const float*)d_in[7];
    const float* c0_w2  = (const float*)d_in[8];
    const float* c0_b2  = (const float*)d_in[9];
    const float* c0_g2  = (const float*)d_in[10];
    const float* c0_be2 = (const float*)d_in[11];
    const float* c0_w3  = (const float*)d_in[12];
    const float* c0_b3  = (const float*)d_in[13];
    const float* cw1    = (const float*)d_in[14];
    const float* cb1    = (const float*)d_in[15];
    const float* cg1    = (const float*)d_in[16];
    const float* cbe1   = (const float*)d_in[17];
    const float* cw2    = (const float*)d_in[18];
    const float* cb2    = (const float*)d_in[19];
    const float* cg2    = (const float*)d_in[20];
    const float* cbe2   = (const float*)d_in[21];
    const float* cw3    = (const float*)d_in[22];
    const float* cb3    = (const float*)d_in[23];
    const float* lin1_w = (const float*)d_in[24];
    const float* lin1_b = (const float*)d_in[25];
    const float* lin2_w = (const float*)d_in[26];
    const float* lin2_b = (const float*)d_in[27];

    const int* src = ei;
    const int* dst = ei + NE;

    char* ws = (char*)d_ws;
    size_t off = 0;
    auto alloc = [&](size_t bytes) {
        void* p = ws + off;
        off += (bytes + 255) & ~(size_t)255;
        return p;
    };
    u16*   bufh  = (u16*)alloc((size_t)NN * H * 2 + 64);   // +64: K-tail overread pad
    u16*   bufa  = (u16*)alloc((size_t)NN * H * 2 + 64);
    float* agg0  = (float*)alloc((size_t)NN * 4 * 4);
    float* stats = (float*)alloc(2 * H * 4);
    float* scale = (float*)alloc(H * 4);
    float* shift = (float*)alloc(H * 4);
    float* pools = (float*)alloc((size_t)NG * 3 * H * 4);
    float* zz    = (float*)alloc((size_t)NG * 600 * 4);
    // padded bf16 weights [8][400][416]: w2_0 | w3_0 | w1[2] | w2[2] | w3[2]
    u16*   wpad  = (u16*)alloc((size_t)8 * 400 * KP * 2);
    int*   deg   = (int*)alloc((size_t)NN * 4);
    int*   rowp  = (int*)alloc((size_t)(NN + 1) * 4);
    int*   cur   = (int*)alloc((size_t)NN * 4);
    int*   csrc  = (int*)alloc((size_t)NE * 4);
    int*   part  = (int*)alloc((size_t)NN * 4);
    int*   btot  = (int*)alloc((size_t)NB1 * 4);

    auto wp = [&](int mat) { return wpad + (size_t)mat * 400 * KP; };

    hipMemsetAsync(deg, 0, (size_t)NN * 4, stream);
    hipMemsetAsync(stats, 0, 2 * H * 4, stream);
    hipMemsetAsync(pools, 0, (size_t)NG * 3 * H * 4, stream);

    k_cvtw_all<<<(8 * 400 * 52 + 255) / 256, 256, 0, stream>>>(c0_w2, c0_w3, cw1, cw2, cw3,
                                                               wpad);

    // CSR build
    k_count<<<(NE + 255) / 256, 256, 0, stream>>>(dst, deg);
    k_scan1<<<NB1, 256, 0, stream>>>(deg, part, btot);
    k_scan2<<<1, 256, 0, stream>>>(btot);
    k_scan3<<<NB1, 256, 0, stream>>>(part, btot, deg, rowp, cur);
    k_scatter<<<(NE + 255) / 256, 256, 0, stream>>>(src, dst, cur, csrc);

    const int ngemm = ((NN + 127) / 128) * 5;   // 1955 blocks
    const int nbn   = (int)(((long)NN * 50 + 255) / 256);

    // layer 0
    k_agg0<<<(NN + 255) / 256, 256, 0, stream>>>(x, rowp, csrc, agg0);
    k_lin0<<<(int)(((long)NN * 100 + 255) / 256), 256, 0, stream>>>(agg0, c0_w1, c0_b1, bufh);
    k_statsv<<<96, 256, 0, stream>>>(bufh, stats);
    k_finalize<<<2, 256, 0, stream>>>(stats, c0_g1, c0_be1, scale, shift);
    k_bnrelu<<<nbn, 256, 0, stream>>>(bufh, scale, shift);
    gemm_mfma<true, false><<<ngemm, 256, 0, stream>>>(bufh, wp(0), c0_b2, bufa, stats,
                                                      nullptr, nullptr, 0, NN);
    k_finalize<<<2, 256, 0, stream>>>(stats, c0_g2, c0_be2, scale, shift);
    k_bnrelu<<<nbn, 256, 0, stream>>>(bufa, scale, shift);
    gemm_mfma<false, true><<<ngemm, 256, 0, stream>>>(bufa, wp(1), c0_b3, bufh, nullptr,
                                                      batch, pools, 0, NN);

    // layers 1..2
    for (int l = 0; l < 2; ++l) {
        k_aggH<<<(NN + 3) / 4, 256, 0, stream>>>(bufh, rowp, csrc, bufa);
        gemm_mfma<true, false><<<ngemm, 256, 0, stream>>>(bufa, wp(2 + l), cb1 + l * H,
                                                          bufh, stats, nullptr, nullptr,
                                                          0, NN);
        k_finalize<<<2, 256, 0, stream>>>(stats, cg1 + l * H, cbe1 + l * H, scale, shift);
        k_bnrelu<<<nbn, 256, 0, stream>>>(bufh, scale, shift);
        gemm_mfma<true, false><<<ngemm, 256, 0, stream>>>(bufh, wp(4 + l), cb2 + l * H,
                                                          bufa, stats, nullptr, nullptr,
                                                          0, NN);
        k_finalize<<<2, 256, 0, stream>>>(stats, cg2 + l * H, cbe2 + l * H, scale, shift);
        k_bnrelu<<<nbn, 256, 0, stream>>>(bufa, scale, shift);
        gemm_mfma<false, true><<<ngemm, 256, 0, stream>>>(bufa, wp(6 + l), cb3 + l * H,
                                                          bufh, nullptr, batch, pools,
                                                          (l + 1) * H, NN);
    }

    // readout
    dim3 gl1(5, NG);
    k_lin1<<<gl1, 256, 0, stream>>>(pools, lin1_w, lin1_b, zz);
    k_lin2<<<NG, 64, 0, stream>>>(zz, lin2_w, lin2_b, (float*)d_out);
}

// Round 7
// 990.540 us; speedup vs baseline: 1.2330x; 1.0359x over previous
//
#include <hip/hip_runtime.h>
#include <hip/hip_bf16.h>
#include <math.h>
#include <cstdint>

static constexpr int NN = 50000;   // nodes
static constexpr int NE = 400000;  // edges
static constexpr int H  = 400;     // hidden dim
static constexpr int NG = 128;     // graphs
static constexpr int NC = 10;      // classes
static constexpr float EPS = 1e-5f;
static constexpr int NB1 = (NN + 255) / 256;   // 196 scan blocks
static constexpr int KP  = 416;                // padded K for weights

typedef unsigned short u16;
typedef __attribute__((ext_vector_type(8))) unsigned short u16x8;
typedef __attribute__((ext_vector_type(4))) unsigned short u16x4;
typedef __attribute__((ext_vector_type(8))) short bf16x8;
typedef __attribute__((ext_vector_type(4))) float f32x4;

__device__ __forceinline__ float bf2f(u16 u) {
    return __uint_as_float(((uint32_t)u) << 16);
}
__device__ __forceinline__ u16 f2bf(float f) {
    uint32_t u = __float_as_uint(f);
    return (u16)((u + 0x7FFFu + ((u >> 16) & 1u)) >> 16);
}
__device__ __forceinline__ void gload_lds16(const void* g, void* lds) {
    __builtin_amdgcn_global_load_lds((const __attribute__((address_space(1))) void*)g,
                                     (__attribute__((address_space(3))) void*)lds, 16, 0, 0);
}

// ---------------- CSR build ----------------

__global__ void k_count(const int* __restrict__ dst, int* __restrict__ deg) {
    int e = blockIdx.x * blockDim.x + threadIdx.x;
    if (e < NE) atomicAdd(&deg[dst[e]], 1);
}

__global__ __launch_bounds__(256) void k_scan1(const int* __restrict__ deg,
                                               int* __restrict__ part,
                                               int* __restrict__ btot) {
    __shared__ int sd[256];
    int t = threadIdx.x;
    int i = blockIdx.x * 256 + t;
    int v = (i < NN) ? deg[i] : 0;
    sd[t] = v;
    __syncthreads();
#pragma unroll
    for (int off = 1; off < 256; off <<= 1) {
        int x = (t >= off) ? sd[t - off] : 0;
        __syncthreads();
        sd[t] += x;
        __syncthreads();
    }
    if (i < NN) part[i] = sd[t];
    if (t == 255) btot[blockIdx.x] = sd[255];
}

__global__ __launch_bounds__(256) void k_scan2(int* __restrict__ btot) {
    __shared__ int sd[256];
    int t = threadIdx.x;
    int v = (t < NB1) ? btot[t] : 0;
    sd[t] = v;
    __syncthreads();
#pragma unroll
    for (int off = 1; off < 256; off <<= 1) {
        int x = (t >= off) ? sd[t - off] : 0;
        __syncthreads();
        sd[t] += x;
        __syncthreads();
    }
    if (t < NB1) btot[t] = sd[t];
}

__global__ __launch_bounds__(256) void k_scan3(const int* __restrict__ part,
                                               const int* __restrict__ btot,
                                               const int* __restrict__ deg,
                                               int* __restrict__ rowp,
                                               int* __restrict__ cur) {
    int i = blockIdx.x * 256 + threadIdx.x;
    if (i < NN) {
        int s = part[i] + (blockIdx.x ? btot[blockIdx.x - 1] : 0);
        rowp[i + 1] = s;
        cur[i] = s - deg[i];
    }
    if (i == 0) rowp[0] = 0;
}

__global__ void k_scatter(const int* __restrict__ src, const int* __restrict__ dst,
                          int* __restrict__ cur, int* __restrict__ csrc) {
    int e = blockIdx.x * blockDim.x + threadIdx.x;
    if (e < NE) {
        int d = dst[e];
        int p = atomicAdd(&cur[d], 1);
        csrc[p] = src[e];
    }
}

// ---------------- weights fp32 -> bf16, padded to [8*400][416] (zeros k>=400) ----------------

__global__ void k_cvtw_all(const float* __restrict__ s0, const float* __restrict__ s1,
                           const float* __restrict__ s2, const float* __restrict__ s3,
                           const float* __restrict__ s4, u16* __restrict__ dst) {
    int i = blockIdx.x * blockDim.x + threadIdx.x;   // over 8*400*52
    if (i >= 8 * 400 * 52) return;
    int rc = i / 52;              // 0..3199 global row
    int c8 = (i % 52) * 8;
    u16x8 o = {0, 0, 0, 0, 0, 0, 0, 0};
    if (c8 < 400) {
        int mat = rc / 400, row = rc % 400;
        const float* s;
        if (mat == 0)      s = s0 + (long)row * 400;
        else if (mat == 1) s = s1 + (long)row * 400;
        else if (mat < 4)  s = s2 + (long)(mat - 2) * 400 * 400 + (long)row * 400;
        else if (mat < 6)  s = s3 + (long)(mat - 4) * 400 * 400 + (long)row * 400;
        else               s = s4 + (long)(mat - 6) * 400 * 400 + (long)row * 400;
        float4 a = *(const float4*)(s + c8);
        float4 b = *(const float4*)(s + c8 + 4);
        o[0] = f2bf(a.x); o[1] = f2bf(a.y); o[2] = f2bf(a.z); o[3] = f2bf(a.w);
        o[4] = f2bf(b.x); o[5] = f2bf(b.y); o[6] = f2bf(b.z); o[7] = f2bf(b.w);
    }
    *(u16x8*)(dst + (long)rc * KP + c8) = o;
}

// ---------------- aggregation ----------------

__global__ void k_agg0(const float* __restrict__ x, const int* __restrict__ rowp,
                       const int* __restrict__ csrc, float* __restrict__ out) {
    int n = blockIdx.x * blockDim.x + threadIdx.x;
    if (n >= NN) return;
    float4 acc = make_float4(0.f, 0.f, 0.f, 0.f);
    int b = rowp[n], e = rowp[n + 1];
    for (int p = b; p < e; ++p) {
        float4 v = ((const float4*)x)[csrc[p]];
        acc.x += v.x; acc.y += v.y; acc.z += v.z; acc.w += v.w;
    }
    ((float4*)out)[n] = acc;
}

// one wave per node; lanes 0..49 each own 8 contiguous features
__global__ __launch_bounds__(256) void k_aggH(const u16* __restrict__ h,
                                              const int* __restrict__ rowp,
                                              const int* __restrict__ csrc,
                                              u16* __restrict__ out) {
    int n = (blockIdx.x << 2) + (threadIdx.x >> 6);
    if (n >= NN) return;
    int l = threadIdx.x & 63;
    if (l >= 50) return;
    int b = rowp[n], e = rowp[n + 1];
    float acc[8] = {0.f, 0.f, 0.f, 0.f, 0.f, 0.f, 0.f, 0.f};
    for (int p = b; p < e; ++p) {
        const u16* r = h + (long)csrc[p] * H + l * 8;
        u16x8 v = *(const u16x8*)r;
#pragma unroll
        for (int q = 0; q < 8; ++q) acc[q] += bf2f(v[q]);
    }
    u16x8 o;
#pragma unroll
    for (int q = 0; q < 8; ++q) o[q] = f2bf(acc[q]);
    *(u16x8*)(out + (long)n * H + l * 8) = o;
}

// ---------------- first linear (K = 4), bf16 out ----------------

__global__ void k_lin0(const float* __restrict__ a4, const float* __restrict__ w,
                       const float* __restrict__ b, u16* __restrict__ out) {
    long i = (long)blockIdx.x * blockDim.x + threadIdx.x;   // over NN*100
    if (i >= (long)NN * 100) return;
    int n = (int)(i / 100), q = (int)(i - (long)n * 100);
    int j0 = q * 4;
    float4 av = ((const float4*)a4)[n];
    u16x4 o;
#pragma unroll
    for (int jj = 0; jj < 4; ++jj) {
        float4 wv = ((const float4*)w)[j0 + jj];
        float s = fmaf(av.x, wv.x, fmaf(av.y, wv.y, fmaf(av.z, wv.z, av.w * wv.w)));
        o[jj] = f2bf(s + b[j0 + jj]);
    }
    *(u16x4*)(out + (long)n * H + j0) = o;
}

// ---------------- BN stats over bf16 buffer (after lin0 only) ----------------

__global__ __launch_bounds__(256) void k_statsv(const u16* __restrict__ z,
                                                float* __restrict__ stats) {
    __shared__ float ls[800];
    int t = threadIdx.x;
    for (int i = t; i < 800; i += 256) ls[i] = 0.f;
    __syncthreads();
    if (t < 250) {
        int sub = t / 50, seg = t % 50;
        float s[8] = {0, 0, 0, 0, 0, 0, 0, 0};
        float q[8] = {0, 0, 0, 0, 0, 0, 0, 0};
        for (int r = blockIdx.x * 5 + sub; r < NN; r += gridDim.x * 5) {
            u16x8 v = *(const u16x8*)(z + (long)r * H + seg * 8);
#pragma unroll
            for (int j = 0; j < 8; ++j) {
                float f = bf2f(v[j]);
                s[j] += f; q[j] += f * f;
            }
        }
#pragma unroll
        for (int j = 0; j < 8; ++j) {
            atomicAdd(&ls[seg * 8 + j], s[j]);
            atomicAdd(&ls[400 + seg * 8 + j], q[j]);
        }
    }
    __syncthreads();
    for (int i = t; i < 800; i += 256) atomicAdd(&stats[i], ls[i]);
}

__global__ void k_finalize(float* __restrict__ stats, const float* __restrict__ g,
                           const float* __restrict__ be, float* __restrict__ scale,
                           float* __restrict__ shift) {
    int j = blockIdx.x * blockDim.x + threadIdx.x;
    if (j >= H) return;
    float m = stats[j] / NN;
    float v = stats[H + j] / NN - m * m;
    v = fmaxf(v, 0.f);
    float rs = rsqrtf(v + EPS);
    float sc = g[j] * rs;
    scale[j] = sc;
    shift[j] = be[j] - m * sc;
    stats[j] = 0.f;          // self-clean for next use
    stats[H + j] = 0.f;
}

// ---------------- BN+ReLU elementwise, in place ----------------

__global__ __launch_bounds__(256) void k_bnrelu(u16* __restrict__ z,
                                                const float* __restrict__ scale,
                                                const float* __restrict__ shift) {
    long i = (long)blockIdx.x * 256 + threadIdx.x;   // over NN*50
    if (i >= (long)NN * 50) return;
    int c8 = (int)(i % 50) * 8;
    u16* p = z + i * 8;
    u16x8 v = *(const u16x8*)p;
    float4 s0 = *(const float4*)(scale + c8);
    float4 s1 = *(const float4*)(scale + c8 + 4);
    float4 h0 = *(const float4*)(shift + c8);
    float4 h1 = *(const float4*)(shift + c8 + 4);
    u16x8 o;
    o[0] = f2bf(fmaxf(fmaf(bf2f(v[0]), s0.x, h0.x), 0.f));
    o[1] = f2bf(fmaxf(fmaf(bf2f(v[1]), s0.y, h0.y), 0.f));
    o[2] = f2bf(fmaxf(fmaf(bf2f(v[2]), s0.z, h0.z), 0.f));
    o[3] = f2bf(fmaxf(fmaf(bf2f(v[3]), s0.w, h0.w), 0.f));
    o[4] = f2bf(fmaxf(fmaf(bf2f(v[4]), s1.x, h1.x), 0.f));
    o[5] = f2bf(fmaxf(fmaf(bf2f(v[5]), s1.y, h1.y), 0.f));
    o[6] = f2bf(fmaxf(fmaf(bf2f(v[6]), s1.z, h1.z), 0.f));
    o[7] = f2bf(fmaxf(fmaf(bf2f(v[7]), s1.w, h1.w), 0.f));
    *(u16x8*)p = o;
}

// ---------------- MFMA GEMM: counted-vmcnt depth-2 pipeline, XOR-swizzled LDS ----------------
// out[n][c] = sum_j A[n][j] * Wp[c][j] + bias[c];  A: M x 400, Wp: 400 x 416 (zero-pad)
// Tile 128x80, BK=32, 13 K-tiles, 3 LDS buffers. Per tile each wave issues its own
// gload_lds set ({4,3,3,3} loads); main loop waits vmcnt(3) (tile s done, tile s+1
// in flight) + raw s_barrier -> HBM latency hidden 2-deep, no full drains.
// LDS slot swizzle: chunk c of row r stored at 16B-slot c ^ ((r>>1)&3) -> each
// 8-lane quarter-wave of ds_read_b128 hits 8 distinct granules (conflict-free).
// Stats/pool LDS arrays alias the (dead) tile buffers after the K-loop.

template <bool STATS, bool POOL>
__global__ __launch_bounds__(256) void gemm_mfma(const u16* __restrict__ A,
                                                 const u16* __restrict__ Wp,
                                                 const float* __restrict__ bias,
                                                 u16* __restrict__ out,
                                                 float* __restrict__ stats,
                                                 const int* __restrict__ batch,
                                                 float* __restrict__ pools,
                                                 int poolOff, int M) {
    constexpr int BUF = 6656;            // u16 per buffer: A 4096 + B 2560
    __shared__ u16 lds[3 * BUF];         // 39,936 B -> 4 blocks/CU

    const int t = threadIdx.x;
    // bijective XCD swizzle (nwg = 1955, not divisible by 8)
    const int nwg = gridDim.x;
    const int q8 = nwg >> 3, r8 = nwg & 7;
    const int xcd = blockIdx.x & 7, jj = blockIdx.x >> 3;
    const int wgid = (xcd < r8 ? xcd * (q8 + 1) : r8 * (q8 + 1) + (xcd - r8) * q8) + jj;
    const int bm = (wgid / 5) * 128;
    const int bn = (wgid % 5) * 80;
    const int w = t >> 6, l = t & 63;

    // staging: lane l writes LDS granule l of its seg; it must load the logical
    // chunk that the swizzle maps to slot (l&3): c_log = (l&3) ^ ((l>>3)&3)
    const int srow = l >> 2;
    const int sck  = ((l & 3) ^ ((l >> 3) & 3)) * 8;

    auto stageTile = [&](int b, int k0) {
        u16* dst = lds + b * BUF;
        long g0 = (long)bm + w * 16 + srow;          // seg w (A)
        long g1 = g0 + 64;                           // seg w+4 (A)
        if (g0 > M - 1) g0 = M - 1;
        if (g1 > M - 1) g1 = M - 1;
        gload_lds16(A + g0 * 400 + k0 + sck, dst + w * 512);
        gload_lds16(A + g1 * 400 + k0 + sck, dst + (w + 4) * 512);
        gload_lds16(Wp + (long)(bn + w * 16 + srow) * KP + k0 + sck,
                    dst + 4096 + w * 512);           // B seg w
        if (w == 0)
            gload_lds16(Wp + (long)(bn + 64 + srow) * KP + k0 + sck,
                        dst + 4096 + 4 * 512);       // B seg 4 (rows 64..79)
    };

    f32x4 acc[2][5];
#pragma unroll
    for (int i = 0; i < 2; ++i)
#pragma unroll
        for (int c = 0; c < 5; ++c)
            acc[i][c] = (f32x4){0.f, 0.f, 0.f, 0.f};

    const int r16 = l & 15;
    const int cc  = l >> 4;                          // logical k-chunk 0..3
    const int swz = r16 * 32 + (((cc ^ ((r16 >> 1) & 3))) << 3);

    auto computeTile = [&](int b) {
        const u16* base = lds + b * BUF;
        const u16* ab = base + w * 1024 + swz;       // segs 2w, 2w+1
        const u16* bb = base + 4096 + swz;
        bf16x8 fa0 = *(const bf16x8*)ab;
        bf16x8 fa1 = *(const bf16x8*)(ab + 512);
        __builtin_amdgcn_s_setprio(1);
#pragma unroll
        for (int c = 0; c < 5; ++c) {
            bf16x8 fb = *(const bf16x8*)(bb + c * 512);
            acc[0][c] = __builtin_amdgcn_mfma_f32_16x16x32_bf16(fa0, fb, acc[0][c], 0, 0, 0);
            acc[1][c] = __builtin_amdgcn_mfma_f32_16x16x32_bf16(fa1, fb, acc[1][c], 0, 0, 0);
        }
        __builtin_amdgcn_s_setprio(0);
    };

    // prologue: tiles 0,1 in flight
    stageTile(0, 0);
    stageTile(1, 32);

    int bc = 0, bs = 2;
#pragma unroll 1
    for (int s = 0; s < 12; ++s) {
        asm volatile("s_waitcnt vmcnt(3)" ::: "memory");   // own tile-s loads done
        __builtin_amdgcn_s_barrier();                      // all waves' tile-s done
        if (s + 2 < 13) stageTile(bs, (s + 2) * 32);
        computeTile(bc);
        if (++bc == 3) bc = 0;
        if (++bs == 3) bs = 0;
    }
    asm volatile("s_waitcnt vmcnt(0)" ::: "memory");
    __builtin_amdgcn_s_barrier();
    computeTile(bc);

    // ---- epilogue (tile LDS now dead; alias stats/pool arrays onto it) ----
    float* sst  = (float*)lds;           // 160 floats
    float* pacc = (float*)lds + 160;     // 480 floats
    __syncthreads();
    if (STATS) for (int i = t; i < 160; i += 256) sst[i] = 0.f;
    if (POOL)  for (int i = t; i < 480; i += 256) pacc[i] = 0.f;
    __syncthreads();

    int sg0 = 0, span = 0;
    int grow[2][4];
    if (POOL) {
        sg0 = batch[min(bm, M - 1)];
        span = batch[min(bm + 127, M - 1)] - sg0 + 1;
#pragma unroll
        for (int i = 0; i < 2; ++i) {
            int rbase = bm + w * 32 + i * 16 + (l >> 4) * 4;
#pragma unroll
            for (int r = 0; r < 4; ++r)
                grow[i][r] = (rbase + r < M) ? batch[rbase + r] : -1;
        }
    }

    // C/D layout: col=lane&15, row=(lane>>4)*4+reg
    float ssum[5], sqq[5];
#pragma unroll
    for (int c = 0; c < 5; ++c) { ssum[c] = 0.f; sqq[c] = 0.f; }
#pragma unroll
    for (int i = 0; i < 2; ++i) {
        const int rbase = bm + w * 32 + i * 16 + (l >> 4) * 4;
#pragma unroll
        for (int c = 0; c < 5; ++c) {
            const int col = bn + c * 16 + (l & 15);
            const float bv = bias[col];
#pragma unroll
            for (int r = 0; r < 4; ++r) {
                const int row = rbase + r;
                if (row < M) {
                    float z = acc[i][c][r] + bv;
                    out[(long)row * H + col] = f2bf(z);
                    if (STATS) { ssum[c] += z; sqq[c] += z * z; }
                    if (POOL) {
                        int g = grow[i][r];
                        if (span <= 6)
                            atomicAdd(&pacc[(g - sg0) * 80 + c * 16 + (l & 15)], z);
                        else
                            atomicAdd(&pools[(long)g * 1200 + poolOff + col], z);
                    }
                }
            }
        }
    }
    if (STATS) {
#pragma unroll
        for (int c = 0; c < 5; ++c) {
            ssum[c] += __shfl_xor(ssum[c], 16); ssum[c] += __shfl_xor(ssum[c], 32);
            sqq[c]  += __shfl_xor(sqq[c], 16);  sqq[c]  += __shfl_xor(sqq[c], 32);
        }
        if (l < 16) {
#pragma unroll
            for (int c = 0; c < 5; ++c) {
                atomicAdd(&sst[c * 16 + l], ssum[c]);
                atomicAdd(&sst[80 + c * 16 + l], sqq[c]);
            }
        }
        __syncthreads();
        if (t < 80)       atomicAdd(&stats[bn + t], sst[t]);
        else if (t < 160) atomicAdd(&stats[H + bn + (t - 80)], sst[t]);
    }
    if (POOL) {
        __syncthreads();
        if (span <= 6) {
            int nsp = span * 80;
            for (int i = t; i < nsp; i += 256) {
                atomicAdd(&pools[(long)(sg0 + i / 80) * 1200 + poolOff + bn + (i % 80)],
                          pacc[i]);
            }
        }
    }
}

// ---------------- readout ----------------

__global__ __launch_bounds__(256) void k_lin1(const float* __restrict__ pools,
                                              const float* __restrict__ w1,
                                              const float* __restrict__ b1,
                                              float* __restrict__ zz) {
    __shared__ __align__(16) float xg[1200];
    int band = blockIdx.x, g = blockIdx.y, t = threadIdx.x;
    for (int i = t; i < 1200; i += 256) xg[i] = pools[(long)g * 1200 + i];
    __syncthreads();
    if (t < 240) {
        int j = band * 120 + (t >> 1);
        int kh = t & 1;
        const float4* wr = (const float4*)(w1 + (long)j * 1200 + kh * 600);
        const float4* xr = (const float4*)(xg + kh * 600);
        float s = 0.f;
        for (int q = 0; q < 150; ++q) {
            float4 a = xr[q], b = wr[q];
            s = fmaf(a.x, b.x, s); s = fmaf(a.y, b.y, s);
            s = fmaf(a.z, b.z, s); s = fmaf(a.w, b.w, s);
        }
        s += __shfl_xor(s, 1);
        if (!kh) zz[(long)g * 600 + j] = fmaxf(s + b1[j], 0.f);
    }
}

__global__ __launch_bounds__(64) void k_lin2(const float* __restrict__ zz,
                                             const float* __restrict__ w2,
                                             const float* __restrict__ b2,
                                             float* __restrict__ out) {
    int g = blockIdx.x;
    int l = threadIdx.x;
    float p[NC];
#pragma unroll
    for (int c = 0; c < NC; ++c) p[c] = 0.f;
    for (int k = l; k < 600; k += 64) {
        float zv = zz[(long)g * 600 + k];
#pragma unroll
        for (int c = 0; c < NC; ++c) p[c] = fmaf(zv, w2[c * 600 + k], p[c]);
    }
#pragma unroll
    for (int c = 0; c < NC; ++c)
#pragma unroll
        for (int o = 32; o; o >>= 1) p[c] += __shfl_xor(p[c], o);
    if (l == 0) {
        float lg[NC];
        float mx = -1e30f;
#pragma unroll
        for (int c = 0; c < NC; ++c) { lg[c] = p[c] + b2[c]; mx = fmaxf(mx, lg[c]); }
        float se = 0.f;
#pragma unroll
        for (int c = 0; c < NC; ++c) se += expf(lg[c] - mx);
        float lse = logf(se);
#pragma unroll
        for (int c = 0; c < NC; ++c) out[(long)g * NC + c] = lg[c] - mx - lse;
    }
}

// ---------------- launch ----------------

extern "C" void kernel_launch(void* const* d_in, const int* in_sizes, int n_in,
                              void* d_out, int out_size, void* d_ws, size_t ws_size,
                              hipStream_t stream) {
    const float* x      = (const float*)d_in[0];
    const int*   ei     = (const int*)d_in[1];
    const int*   batch  = (const int*)d_in[2];
    const float* c0_w1  = (const float*)d_in[4];
    const float* c0_b1  = (const float*)d_in[5];
    const float* c0_g1  = (const float*)d_in[6];
    const float* c0_be1 = (const float*)d_in[7];
    const float* c0_w2  = (const float*)d_in[8];
    const float* c0_b2  = (const float*)d_in[9];
    const float* c0_g2  = (const float*)d_in[10];
    const float* c0_be2 = (const float*)d_in[11];
    const float* c0_w3  = (const float*)d_in[12];
    const float* c0_b3  = (const float*)d_in[13];
    const float* cw1    = (const float*)d_in[14];
    const float* cb1    = (const float*)d_in[15];
    const float* cg1    = (const float*)d_in[16];
    const float* cbe1   = (const float*)d_in[17];
    const float* cw2    = (const float*)d_in[18];
    const float* cb2    = (const float*)d_in[19];
    const float* cg2    = (const float*)d_in[20];
    const float* cbe2   = (const float*)d_in[21];
    const float* cw3    = (const float*)d_in[22];
    const float* cb3    = (const float*)d_in[23];
    const float* lin1_w = (const float*)d_in[24];
    const float* lin1_b = (const float*)d_in[25];
    const float* lin2_w = (const float*)d_in[26];
    const float* lin2_b = (const float*)d_in[27];

    const int* src = ei;
    const int* dst = ei + NE;

    char* ws = (char*)d_ws;
    size_t off = 0;
    auto alloc = [&](size_t bytes) {
        void* p = ws + off;
        off += (bytes + 255) & ~(size_t)255;
        return p;
    };
    u16*   bufh  = (u16*)alloc((size_t)NN * H * 2 + 64);   // +64: K-tail overread pad
    u16*   bufa  = (u16*)alloc((size_t)NN * H * 2 + 64);
    float* agg0  = (float*)alloc((size_t)NN * 4 * 4);
    float* stats = (float*)alloc(2 * H * 4);
    float* scale = (float*)alloc(H * 4);
    float* shift = (float*)alloc(H * 4);
    float* pools = (float*)alloc((size_t)NG * 3 * H * 4);
    float* zz    = (float*)alloc((size_t)NG * 600 * 4);
    // padded bf16 weights [8][400][416]: w2_0 | w3_0 | w1[2] | w2[2] | w3[2]
    u16*   wpad  = (u16*)alloc((size_t)8 * 400 * KP * 2);
    int*   deg   = (int*)alloc((size_t)NN * 4);
    int*   rowp  = (int*)alloc((size_t)(NN + 1) * 4);
    int*   cur   = (int*)alloc((size_t)NN * 4);
    int*   csrc  = (int*)alloc((size_t)NE * 4);
    int*   part  = (int*)alloc((size_t)NN * 4);
    int*   btot  = (int*)alloc((size_t)NB1 * 4);

    auto wp = [&](int mat) { return wpad + (size_t)mat * 400 * KP; };

    hipMemsetAsync(deg, 0, (size_t)NN * 4, stream);
    hipMemsetAsync(stats, 0, 2 * H * 4, stream);
    hipMemsetAsync(pools, 0, (size_t)NG * 3 * H * 4, stream);

    k_cvtw_all<<<(8 * 400 * 52 + 255) / 256, 256, 0, stream>>>(c0_w2, c0_w3, cw1, cw2, cw3,
                                                               wpad);

    // CSR build
    k_count<<<(NE + 255) / 256, 256, 0, stream>>>(dst, deg);
    k_scan1<<<NB1, 256, 0, stream>>>(deg, part, btot);
    k_scan2<<<1, 256, 0, stream>>>(btot);
    k_scan3<<<NB1, 256, 0, stream>>>(part, btot, deg, rowp, cur);
    k_scatter<<<(NE + 255) / 256, 256, 0, stream>>>(src, dst, cur, csrc);

    const int ngemm = ((NN + 127) / 128) * 5;   // 1955 blocks
    const int nbn   = (int)(((long)NN * 50 + 255) / 256);

    // layer 0
    k_agg0<<<(NN + 255) / 256, 256, 0, stream>>>(x, rowp, csrc, agg0);
    k_lin0<<<(int)(((long)NN * 100 + 255) / 256), 256, 0, stream>>>(agg0, c0_w1, c0_b1, bufh);
    k_statsv<<<96, 256, 0, stream>>>(bufh, stats);
    k_finalize<<<2, 256, 0, stream>>>(stats, c0_g1, c0_be1, scale, shift);
    k_bnrelu<<<nbn, 256, 0, stream>>>(bufh, scale, shift);
    gemm_mfma<true, false><<<ngemm, 256, 0, stream>>>(bufh, wp(0), c0_b2, bufa, stats,
                                                      nullptr, nullptr, 0, NN);
    k_finalize<<<2, 256, 0, stream>>>(stats, c0_g2, c0_be2, scale, shift);
    k_bnrelu<<<nbn, 256, 0, stream>>>(bufa, scale, shift);
    gemm_mfma<false, true><<<ngemm, 256, 0, stream>>>(bufa, wp(1), c0_b3, bufh, nullptr,
                                                      batch, pools, 0, NN);

    // layers 1..2
    for (int l = 0; l < 2; ++l) {
        k_aggH<<<(NN + 3) / 4, 256, 0, stream>>>(bufh, rowp, csrc, bufa);
        gemm_mfma<true, false><<<ngemm, 256, 0, stream>>>(bufa, wp(2 + l), cb1 + l * H,
                                                          bufh, stats, nullptr, nullptr,
                                                          0, NN);
        k_finalize<<<2, 256, 0, stream>>>(stats, cg1 + l * H, cbe1 + l * H, scale, shift);
        k_bnrelu<<<nbn, 256, 0, stream>>>(bufh, scale, shift);
        gemm_mfma<true, false><<<ngemm, 256, 0, stream>>>(bufh, wp(4 + l), cb2 + l * H,
                                                          bufa, stats, nullptr, nullptr,
                                                          0, NN);
        k_finalize<<<2, 256, 0, stream>>>(stats, cg2 + l * H, cbe2 + l * H, scale, shift);
        k_bnrelu<<<nbn, 256, 0, stream>>>(bufa, scale, shift);
        gemm_mfma<false, true><<<ngemm, 256, 0, stream>>>(bufa, wp(6 + l), cb3 + l * H,
                                                          bufh, nullptr, batch, pools,
                                                          (l + 1) * H, NN);
    }

    // readout
    dim3 gl1(5, NG);
    k_lin1<<<gl1, 256, 0, stream>>>(pools, lin1_w, lin1_b, zz);
    k_lin2<<<NG, 64, 0, stream>>>(zz, lin2_w, lin2_b, (float*)d_out);
}